// Round 5
// baseline (391.666 us; speedup 1.0000x reference)
//
#include <hip/hip_runtime.h>

// HypergraphModel on MI355X.
// R17: revert scheduling to R14 (degree-sort refuted: R16 isolated it to
//      -14us in k_seg_agg; fused already reverted). New lever: double
//      per-wave MLP in the gather engine. Each thread now owns a 32B row
//      slice (two uint4) instead of 16B -> 16 loads in flight per batch
//      window instead of 8; half the lanes per segment, 2x segments per
//      wave/block. Column accumulation order unchanged -> bit-identical.
//      Fused kernels: 2x segments/block (Ws amortized 2x; lv/lk 64 seg,
//      34.8KB LDS, 4 blk/CU; ln 128 seg, 28.7KB LDS, 5 blk/CU).

#define NN 100000
#define NE 100000
#define NP 1600000
#define NBK  391   // buckets per side (256 ids each); NBK*256 = 100,096
#define BCAP 4608  // bucket cap (mean 4096, +8 sigma)
#define CCAP 48    // padded CSR row stride (Poisson(16) + >8 sigma)

// ws offsets in 4-byte words (sizes in words) — non-overlapping (R14 layout):
#define O_GCURE 0              // 512  (zeroed)
#define O_GCURN 512            // 512  (zeroed)
#define O_NORM  1024           // 64   (zeroed)
#define O_DEGE  1088           // 100,000
#define O_DEGN  101088         // 100,000
#define O_BINV  201088         // 100,000
#define O_DINV  301088         // 100,000
#define O_BKTE  401088         // NBK*BCAP = 1,801,728
#define O_BKTN  2202816        // 1,801,728
#define O_CSRE  4004544        // NE*CCAP = 4,800,000
#define O_CSRN  8804544        // 4,800,000
#define O_XB    13604544       // bf16 100000x32 = 1,600,000 words
#define O_T     15204544       // bf16 100000x64 = 3,200,000 words
#define O_HE    18404544       // bf16 100000x64 = 3,200,000 words
#define O_C1    21604544       // fp32 64x32 = 2,048
#define O_C1B   21606592       // fp32 32
#define O_A     21606624       // bf16 100000x64 = 1,600,000 words
// end 23,206,624 words = 92.8 MB (proven envelope)

typedef unsigned int uint32;

__device__ __forceinline__ float b2f_lo(uint32 u) { return __uint_as_float(u << 16); }
__device__ __forceinline__ float b2f_hi(uint32 u) { return __uint_as_float(u & 0xFFFF0000u); }
__device__ __forceinline__ uint32 f2b(float f) {  // RNE fp32 -> bf16
  uint32 b = __float_as_uint(f);
  return (b + 0x7FFFu + ((b >> 16) & 1u)) >> 16;
}
__device__ __forceinline__ uint32 pack2(float lo, float hi) {
  return f2b(lo) | (f2b(hi) << 16);
}

// 16-elem gather-accumulate over a padded-CSR segment (bf16 rows, ROWU uints
// per row, 32B = two uint4 per lane). a[0..15] must be zeroed by caller.
// Index-prefetch software pipeline (R14) + 16 loads in flight per batch (R17).
template <int ROWU>
__device__ __forceinline__ void gather16(const uint32* __restrict__ base,
                                         const int* __restrict__ csr,
                                         int beg, int end, float* a) {
#define ACC2(q, r)                                        \
  a[0]  += b2f_lo(q.x); a[1]  += b2f_hi(q.x);             \
  a[2]  += b2f_lo(q.y); a[3]  += b2f_hi(q.y);             \
  a[4]  += b2f_lo(q.z); a[5]  += b2f_hi(q.z);             \
  a[6]  += b2f_lo(q.w); a[7]  += b2f_hi(q.w);             \
  a[8]  += b2f_lo(r.x); a[9]  += b2f_hi(r.x);             \
  a[10] += b2f_lo(r.y); a[11] += b2f_hi(r.y);             \
  a[12] += b2f_lo(r.z); a[13] += b2f_hi(r.z);             \
  a[14] += b2f_lo(r.w); a[15] += b2f_hi(r.w);
  int p = beg;
  int nfull = (end - beg) >> 3;
  int4 ia, ib;
  bool have = false;
  if (nfull > 0) {
    ia = *(const int4*)(csr + p);
    ib = *(const int4*)(csr + p + 4);
    for (int k = 0; k < nfull; ++k) {
      const uint32* b0 = base + (long)ia.x * ROWU;
      const uint32* b1 = base + (long)ia.y * ROWU;
      const uint32* b2 = base + (long)ia.z * ROWU;
      const uint32* b3 = base + (long)ia.w * ROWU;
      const uint32* b4 = base + (long)ib.x * ROWU;
      const uint32* b5 = base + (long)ib.y * ROWU;
      const uint32* b6 = base + (long)ib.z * ROWU;
      const uint32* b7 = base + (long)ib.w * ROWU;
      uint4 q0 = *(const uint4*)(b0); uint4 r0 = *(const uint4*)(b0 + 4);
      uint4 q1 = *(const uint4*)(b1); uint4 r1 = *(const uint4*)(b1 + 4);
      uint4 q2 = *(const uint4*)(b2); uint4 r2 = *(const uint4*)(b2 + 4);
      uint4 q3 = *(const uint4*)(b3); uint4 r3 = *(const uint4*)(b3 + 4);
      uint4 q4 = *(const uint4*)(b4); uint4 r4 = *(const uint4*)(b4 + 4);
      uint4 q5 = *(const uint4*)(b5); uint4 r5 = *(const uint4*)(b5 + 4);
      uint4 q6 = *(const uint4*)(b6); uint4 r6 = *(const uint4*)(b6 + 4);
      uint4 q7 = *(const uint4*)(b7); uint4 r7 = *(const uint4*)(b7 + 4);
      // prefetch next batch's indices while rows are in flight (padded CSR
      // makes the address safe; values only consumed if used).
      ia = *(const int4*)(csr + p + 8);
      ib = *(const int4*)(csr + p + 12);
      ACC2(q0, r0) ACC2(q1, r1) ACC2(q2, r2) ACC2(q3, r3)
      ACC2(q4, r4) ACC2(q5, r5) ACC2(q6, r6) ACC2(q7, r7)
      p += 8;
    }
    have = true;
  }
  int rem = end - p;  // 0..7
  if (rem > 0) {
    if (!have) {
      ia = *(const int4*)(csr + p);
      ib = *(const int4*)(csr + p + 4);
    }
    // ia/ib hold csr[p..p+7]; issue all valid row loads before any ACC.
    uint4 z = {0u, 0u, 0u, 0u};
    uint4 q0 = z, q1 = z, q2 = z, q3 = z, q4 = z, q5 = z, q6 = z;
    uint4 r0 = z, r1 = z, r2 = z, r3 = z, r4 = z, r5 = z, r6 = z;
    {
      const uint32* b0 = base + (long)ia.x * ROWU;
      q0 = *(const uint4*)(b0); r0 = *(const uint4*)(b0 + 4);
    }
    if (rem > 1) { const uint32* b1 = base + (long)ia.y * ROWU;
      q1 = *(const uint4*)(b1); r1 = *(const uint4*)(b1 + 4); }
    if (rem > 2) { const uint32* b2 = base + (long)ia.z * ROWU;
      q2 = *(const uint4*)(b2); r2 = *(const uint4*)(b2 + 4); }
    if (rem > 3) { const uint32* b3 = base + (long)ia.w * ROWU;
      q3 = *(const uint4*)(b3); r3 = *(const uint4*)(b3 + 4); }
    if (rem > 4) { const uint32* b4 = base + (long)ib.x * ROWU;
      q4 = *(const uint4*)(b4); r4 = *(const uint4*)(b4 + 4); }
    if (rem > 5) { const uint32* b5 = base + (long)ib.y * ROWU;
      q5 = *(const uint4*)(b5); r5 = *(const uint4*)(b5 + 4); }
    if (rem > 6) { const uint32* b6 = base + (long)ib.z * ROWU;
      q6 = *(const uint4*)(b6); r6 = *(const uint4*)(b6 + 4); }
    ACC2(q0, r0) ACC2(q1, r1) ACC2(q2, r2) ACC2(q3, r3)
    ACC2(q4, r4) ACC2(q5, r5) ACC2(q6, r6)
  }
#undef ACC2
}

// ---- k_front: bucketize (blocks 0..NBK-1) + compose (block NBK) +
//      cast x->bf16 (blocks NBK+1 ..). All independent.
#define CASTB ((NN * 32 / 8 + 255) / 256)  // 1563
__global__ __launch_bounds__(256) void k_front(const int* __restrict__ nidx,
                                               const int* __restrict__ eidx,
                                               int* __restrict__ gcurE,
                                               int* __restrict__ gcurN,
                                               int* __restrict__ bktE,
                                               int* __restrict__ bktN,
                                               const float* __restrict__ Wmu,
                                               const float* __restrict__ bmu,
                                               const float* __restrict__ dW1,
                                               const float* __restrict__ db1,
                                               float* __restrict__ C1,
                                               float* __restrict__ c1,
                                               const float* __restrict__ x,
                                               uint32* __restrict__ xb) {
  __shared__ int cntE[NBK], cntN[NBK], curE[NBK], curN[NBK];
  if (blockIdx.x < NBK) {
    for (int i = threadIdx.x; i < NBK; i += 256) { cntE[i] = 0; cntN[i] = 0; }
    __syncthreads();
    int base = blockIdx.x * 4096 + threadIdx.x * 16;
    int n[16], e[16];
    int cnt = 0;
    if (base + 16 <= NP) {
#pragma unroll
      for (int q = 0; q < 4; ++q) {
        int4 a = *(const int4*)(nidx + base + 4 * q);
        int4 b = *(const int4*)(eidx + base + 4 * q);
        n[4 * q + 0] = a.x; n[4 * q + 1] = a.y; n[4 * q + 2] = a.z; n[4 * q + 3] = a.w;
        e[4 * q + 0] = b.x; e[4 * q + 1] = b.y; e[4 * q + 2] = b.z; e[4 * q + 3] = b.w;
      }
      cnt = 16;
    } else {
      for (int i = 0; i < 16 && base + i < NP; ++i) {
        n[i] = nidx[base + i];
        e[i] = eidx[base + i];
        ++cnt;
      }
    }
    for (int i = 0; i < cnt; ++i) {
      atomicAdd(&cntE[e[i] >> 8], 1);
      atomicAdd(&cntN[n[i] >> 8], 1);
    }
    __syncthreads();
    for (int i = threadIdx.x; i < NBK; i += 256) {
      curE[i] = atomicAdd(&gcurE[i], cntE[i]);
      curN[i] = atomicAdd(&gcurN[i], cntN[i]);
    }
    __syncthreads();
    for (int i = 0; i < cnt; ++i) {
      int be = e[i] >> 8, bn = n[i] >> 8;
      int se = atomicAdd(&curE[be], 1);
      if (se < BCAP) bktE[be * BCAP + se] = ((e[i] & 255) << 24) | n[i];
      int sn = atomicAdd(&curN[bn], 1);
      if (sn < BCAP) bktN[bn * BCAP + sn] = ((n[i] & 255) << 24) | e[i];
    }
  } else if (blockIdx.x == NBK) {
    int t = threadIdx.x;
    for (int idx = t; idx < 64 * 32; idx += 256) {
      int i = idx >> 5, j = idx & 31;
      float s = 0.f;
      for (int k = 0; k < 64; ++k) s += Wmu[i * 64 + k] * dW1[k * 32 + j];
      C1[idx] = s;
    }
    if (t < 32) {
      float s = db1[t];
      for (int k = 0; k < 64; ++k) s += bmu[k] * dW1[k * 32 + t];
      c1[t] = s;
    }
  } else {
    int t = (blockIdx.x - NBK - 1) * 256 + threadIdx.x;
    if (t < NN * 32 / 8) {
      const float4 f0 = *(const float4*)(x + (long)t * 8);
      const float4 f1 = *(const float4*)(x + (long)t * 8 + 4);
      uint4 o;
      o.x = pack2(f0.x, f0.y);
      o.y = pack2(f0.z, f0.w);
      o.z = pack2(f1.x, f1.y);
      o.w = pack2(f1.z, f1.w);
      *(uint4*)(xb + (long)t * 4) = o;
    }
  }
}

// ---- Pass B: per-bucket padded-CSR build + deg + 1/deg (R14 form).
__global__ __launch_bounds__(256) void k_csr2(const int* __restrict__ gcurE,
                                              const int* __restrict__ gcurN,
                                              const int* __restrict__ bktE,
                                              const int* __restrict__ bktN,
                                              int* __restrict__ csrE,
                                              int* __restrict__ csrN,
                                              int* __restrict__ degE,
                                              int* __restrict__ degN,
                                              float* __restrict__ invE,
                                              float* __restrict__ invN) {
  int bb = blockIdx.x;
  bool es = bb < NBK;
  int b = es ? bb : bb - NBK;
  const int* gcur = es ? gcurE : gcurN;
  const int* bkt  = es ? bktE : bktN;
  int*   csr = es ? csrE : csrN;
  int*   deg = es ? degE : degN;
  float* inv = es ? invE : invN;

  __shared__ int ent[BCAP];
  __shared__ int cnt[256], cur[256];
  int m = gcur[b];
  if (m > BCAP) m = BCAP;
  for (int i = threadIdx.x; i < m; i += 256) ent[i] = bkt[b * BCAP + i];
  cnt[threadIdx.x] = 0;
  __syncthreads();
  for (int i = threadIdx.x; i < m; i += 256)
    atomicAdd(&cnt[((unsigned)ent[i]) >> 24], 1);
  __syncthreads();
  int id = (b << 8) + threadIdx.x;
  if (id < NN) {  // NN == NE
    int d = cnt[threadIdx.x];
    deg[id] = d < CCAP ? d : CCAP;
    inv[id] = d > 0 ? 1.0f / (float)d : 0.0f;
  }
  cur[threadIdx.x] = 0;
  __syncthreads();
  for (int i = threadIdx.x; i < m; i += 256) {
    unsigned v = (unsigned)ent[i];
    int loc = v >> 24;
    int payload = v & 0xFFFFFF;
    int slot = atomicAdd(&cur[loc], 1);
    if (slot < CCAP) csr[(long)((b << 8) + loc) * CCAP + slot] = payload;
  }
}

// Edge-side gather-reduce, bf16 in / bf16 out. 32B slice per lane (R17).
template <int W>
__global__ __launch_bounds__(256) void k_seg_agg(const uint32* __restrict__ tb,
                                                 const int* __restrict__ csr,
                                                 const int* __restrict__ deg,
                                                 const float* __restrict__ inv,
                                                 uint32* __restrict__ dstb) {
  constexpr int LANES = W / 16;
  constexpr int ROWU = W / 2;
  int g = blockIdx.x * 256 + threadIdx.x;
  int s = g / LANES;
  int lane = g % LANES;
  if (s >= NE) return;
  int d = deg[s];
  float a[16];
#pragma unroll
  for (int j = 0; j < 16; ++j) a[j] = 0.f;
  gather16<ROWU>(tb + (long)lane * 8, csr, s * CCAP, s * CCAP + d, a);
  float sc = inv[s];
  uint4 o0, o1;
  o0.x = pack2(a[0] * sc, a[1] * sc);
  o0.y = pack2(a[2] * sc, a[3] * sc);
  o0.z = pack2(a[4] * sc, a[5] * sc);
  o0.w = pack2(a[6] * sc, a[7] * sc);
  o1.x = pack2(a[8] * sc, a[9] * sc);
  o1.y = pack2(a[10] * sc, a[11] * sc);
  o1.z = pack2(a[12] * sc, a[13] * sc);
  o1.w = pack2(a[14] * sc, a[15] * sc);
  *(uint4*)(dstb + (long)s * ROWU + lane * 8) = o0;
  *(uint4*)(dstb + (long)s * ROWU + lane * 8 + 4) = o1;
}

// ---- Fused node-agg (32-wide) + GEMM(32->64) + LN + leaky -> bf16 t.
// R17: 128 segments/block, 2 lanes/segment (32B slices).
#define R32 40
__global__ __launch_bounds__(256) void k_agg_ln(
    const uint32* __restrict__ he, const int* __restrict__ csr,
    const int* __restrict__ deg, const float* __restrict__ inv,
    const float* __restrict__ W1, const float* __restrict__ b1,
    const float* __restrict__ g1, const float* __restrict__ be1,
    uint32* __restrict__ h) {
  __shared__ float Ws[32 * 64];
  __shared__ __align__(16) float rows[128 * R32];
  for (int i = threadIdx.x; i < 32 * 64; i += 256) Ws[i] = W1[i];
  int sl = threadIdx.x >> 1;
  int lane = threadIdx.x & 1;
  int s = blockIdx.x * 128 + sl;
  if (s < NN) {
    int d = deg[s];
    float a[16];
#pragma unroll
    for (int j = 0; j < 16; ++j) a[j] = 0.f;
    gather16<16>(he + (long)lane * 8, csr, s * CCAP, s * CCAP + d, a);
    float sc = inv[s];
    float* rw = &rows[sl * R32 + lane * 16];
#pragma unroll
    for (int j = 0; j < 4; ++j) {
      float4 o = {a[4 * j + 0] * sc, a[4 * j + 1] * sc,
                  a[4 * j + 2] * sc, a[4 * j + 3] * sc};
      *(float4*)(rw + 4 * j) = o;
    }
  }
  __syncthreads();
#pragma unroll
  for (int pass = 0; pass < 8; ++pass) {
    int rl = pass * 16 + (threadIdx.x >> 4);
    int r = blockIdx.x * 128 + rl;
    int l = (threadIdx.x & 15) * 4;
    float vx = b1[l + 0], vy = b1[l + 1], vz = b1[l + 2], vw = b1[l + 3];
    const float* row = &rows[rl * R32];
#pragma unroll
    for (int kk = 0; kk < 8; ++kk) {
      float4 rv = *(const float4*)(row + 4 * kk);
      const float* w0 = &Ws[(4 * kk + 0) * 64 + l];
      const float* w1 = &Ws[(4 * kk + 1) * 64 + l];
      const float* w2 = &Ws[(4 * kk + 2) * 64 + l];
      const float* w3 = &Ws[(4 * kk + 3) * 64 + l];
      vx += rv.x * w0[0] + rv.y * w1[0] + rv.z * w2[0] + rv.w * w3[0];
      vy += rv.x * w0[1] + rv.y * w1[1] + rv.z * w2[1] + rv.w * w3[1];
      vz += rv.x * w0[2] + rv.y * w1[2] + rv.z * w2[2] + rv.w * w3[2];
      vw += rv.x * w0[3] + rv.y * w1[3] + rv.z * w2[3] + rv.w * w3[3];
    }
    float sm = vx + vy + vz + vw;
    float s2 = vx * vx + vy * vy + vz * vz + vw * vw;
    for (int m = 1; m <= 8; m <<= 1) {
      sm += __shfl_xor(sm, m, 64);
      s2 += __shfl_xor(s2, m, 64);
    }
    float mean = sm * (1.0f / 64.0f);
    float var = s2 * (1.0f / 64.0f) - mean * mean;
    float rstd = rsqrtf(var + 1e-5f);
    if (r < NN) {
      float ox = (vx - mean) * rstd * g1[l + 0] + be1[l + 0];
      float oy = (vy - mean) * rstd * g1[l + 1] + be1[l + 1];
      float oz = (vz - mean) * rstd * g1[l + 2] + be1[l + 2];
      float ow = (vw - mean) * rstd * g1[l + 3] + be1[l + 3];
      ox = ox >= 0.f ? ox : 0.01f * ox;
      oy = oy >= 0.f ? oy : 0.01f * oy;
      oz = oz >= 0.f ? oz : 0.01f * oz;
      ow = ow >= 0.f ? ow : 0.01f * ow;
      uint2 o = {pack2(ox, oy), pack2(oz, ow)};
      *(uint2*)(h + (long)r * 32 + (l >> 1)) = o;
    }
  }
}

// ---- Fused node-agg (64-wide) + GEMM(64->64) + leaky -> bf16 t.
// R17: 64 segments/block, 4 lanes/segment (32B slices).
#define R64 72
__global__ __launch_bounds__(256) void k_agg_lk(
    const uint32* __restrict__ he, const int* __restrict__ csr,
    const int* __restrict__ deg, const float* __restrict__ inv,
    const float* __restrict__ W2, const float* __restrict__ b2,
    uint32* __restrict__ h2) {
  __shared__ float Ws[64 * 64];
  __shared__ __align__(16) float rows[64 * R64];
  for (int i = threadIdx.x; i < 64 * 64; i += 256) Ws[i] = W2[i];
  int sl = threadIdx.x >> 2;
  int lane = threadIdx.x & 3;
  int s = blockIdx.x * 64 + sl;
  if (s < NN) {
    int d = deg[s];
    float a[16];
#pragma unroll
    for (int j = 0; j < 16; ++j) a[j] = 0.f;
    gather16<32>(he + (long)lane * 8, csr, s * CCAP, s * CCAP + d, a);
    float sc = inv[s];
    float* rw = &rows[sl * R64 + lane * 16];
#pragma unroll
    for (int j = 0; j < 4; ++j) {
      float4 o = {a[4 * j + 0] * sc, a[4 * j + 1] * sc,
                  a[4 * j + 2] * sc, a[4 * j + 3] * sc};
      *(float4*)(rw + 4 * j) = o;
    }
  }
  __syncthreads();
#pragma unroll
  for (int pass = 0; pass < 4; ++pass) {
    int rl = pass * 16 + (threadIdx.x >> 4);
    int r = blockIdx.x * 64 + rl;
    int l = (threadIdx.x & 15) * 4;
    float vx = b2[l + 0], vy = b2[l + 1], vz = b2[l + 2], vw = b2[l + 3];
    const float* row = &rows[rl * R64];
#pragma unroll
    for (int kk = 0; kk < 16; ++kk) {
      float4 rv = *(const float4*)(row + 4 * kk);
      const float* w0 = &Ws[(4 * kk + 0) * 64 + l];
      const float* w1 = &Ws[(4 * kk + 1) * 64 + l];
      const float* w2 = &Ws[(4 * kk + 2) * 64 + l];
      const float* w3 = &Ws[(4 * kk + 3) * 64 + l];
      vx += rv.x * w0[0] + rv.y * w1[0] + rv.z * w2[0] + rv.w * w3[0];
      vy += rv.x * w0[1] + rv.y * w1[1] + rv.z * w2[1] + rv.w * w3[1];
      vz += rv.x * w0[2] + rv.y * w1[2] + rv.z * w2[2] + rv.w * w3[2];
      vw += rv.x * w0[3] + rv.y * w1[3] + rv.z * w2[3] + rv.w * w3[3];
    }
    if (r < NN) {
      vx = vx >= 0.f ? vx : 0.01f * vx;
      vy = vy >= 0.f ? vy : 0.01f * vy;
      vz = vz >= 0.f ? vz : 0.01f * vz;
      vw = vw >= 0.f ? vw : 0.01f * vw;
      uint2 o = {pack2(vx, vy), pack2(vz, vw)};
      *(uint2*)(h2 + (long)r * 32 + (l >> 1)) = o;
    }
  }
}

// ---- Fused node-agg (64-wide) + logvar GEMM; emits bf16 a3 for decode.
// R17: 64 segments/block, 4 lanes/segment (32B slices).
__global__ __launch_bounds__(256) void k_agg_lv(
    const uint32* __restrict__ he, const int* __restrict__ csr,
    const int* __restrict__ deg, const float* __restrict__ inv,
    const float* __restrict__ Wlv, const float* __restrict__ blv,
    uint32* __restrict__ a3b, float* __restrict__ lv) {
  __shared__ float Ws[64 * 64];
  __shared__ __align__(16) float rows[64 * R64];
  for (int i = threadIdx.x; i < 64 * 64; i += 256) Ws[i] = Wlv[i];
  int sl = threadIdx.x >> 2;
  int lane = threadIdx.x & 3;
  int s = blockIdx.x * 64 + sl;
  if (s < NN) {
    int d = deg[s];
    float a[16];
#pragma unroll
    for (int j = 0; j < 16; ++j) a[j] = 0.f;
    gather16<32>(he + (long)lane * 8, csr, s * CCAP, s * CCAP + d, a);
    float sc = inv[s];
    float o[16];
#pragma unroll
    for (int j = 0; j < 16; ++j) o[j] = a[j] * sc;
    float* rw = &rows[sl * R64 + lane * 16];
#pragma unroll
    for (int j = 0; j < 4; ++j) {
      float4 v = {o[4 * j + 0], o[4 * j + 1], o[4 * j + 2], o[4 * j + 3]};
      *(float4*)(rw + 4 * j) = v;
    }
    // bf16 a3 side-write for k_decode (two uint4 = 16 bf16 per lane)
    uint4 ob0, ob1;
    ob0.x = pack2(o[0], o[1]);   ob0.y = pack2(o[2], o[3]);
    ob0.z = pack2(o[4], o[5]);   ob0.w = pack2(o[6], o[7]);
    ob1.x = pack2(o[8], o[9]);   ob1.y = pack2(o[10], o[11]);
    ob1.z = pack2(o[12], o[13]); ob1.w = pack2(o[14], o[15]);
    *(uint4*)(a3b + (long)s * 32 + lane * 8) = ob0;
    *(uint4*)(a3b + (long)s * 32 + lane * 8 + 4) = ob1;
  }
  __syncthreads();
#pragma unroll
  for (int pass = 0; pass < 4; ++pass) {
    int rl = pass * 16 + (threadIdx.x >> 4);
    int r = blockIdx.x * 64 + rl;
    int l = (threadIdx.x & 15) * 4;
    float vx = blv[l + 0], vy = blv[l + 1], vz = blv[l + 2], vw = blv[l + 3];
    const float* row = &rows[rl * R64];
#pragma unroll
    for (int kk = 0; kk < 16; ++kk) {
      float4 rv = *(const float4*)(row + 4 * kk);
      const float* w0 = &Ws[(4 * kk + 0) * 64 + l];
      const float* w1 = &Ws[(4 * kk + 1) * 64 + l];
      const float* w2 = &Ws[(4 * kk + 2) * 64 + l];
      const float* w3 = &Ws[(4 * kk + 3) * 64 + l];
      vx += rv.x * w0[0] + rv.y * w1[0] + rv.z * w2[0] + rv.w * w3[0];
      vy += rv.x * w0[1] + rv.y * w1[1] + rv.z * w2[1] + rv.w * w3[1];
      vz += rv.x * w0[2] + rv.y * w1[2] + rv.z * w2[2] + rv.w * w3[2];
      vw += rv.x * w0[3] + rv.y * w1[3] + rv.z * w2[3] + rv.w * w3[3];
    }
    if (r < NN) {
      float4 o = {vx, vy, vz, vw};
      *(float4*)(&lv[(long)r * 64 + l]) = o;
    }
  }
}

// decode from bf16 a3 via composed C1/c1; one thread per row; norm accumulate.
__global__ __launch_bounds__(256) void k_decode(
    const uint32* __restrict__ a3b, const float* __restrict__ C1,
    const float* __restrict__ c1, const float* __restrict__ dW2,
    const float* __restrict__ db2, const float* __restrict__ dW3,
    const float* __restrict__ db3, float* __restrict__ out,
    float* __restrict__ norm_acc) {
  __shared__ float C1s[64 * 32];
  __shared__ float W2s[32 * 8];
  __shared__ float W3s[8];
  __shared__ float c1s[32];
  __shared__ float b2s[8];
  __shared__ float b3s;
  for (int i = threadIdx.x; i < 2048; i += 256) C1s[i] = C1[i];
  if (threadIdx.x < 256) W2s[threadIdx.x] = dW2[threadIdx.x];
  if (threadIdx.x < 32) c1s[threadIdx.x] = c1[threadIdx.x];
  if (threadIdx.x < 8) {
    W3s[threadIdx.x] = dW3[threadIdx.x];
    b2s[threadIdx.x] = db2[threadIdx.x];
  }
  if (threadIdx.x == 0) b3s = db3[0];
  __syncthreads();
  int n = blockIdx.x * 256 + threadIdx.x;
  float dval = 0.0f;
  if (n < NN) {
    float acc[32];
#pragma unroll
    for (int j = 0; j < 32; ++j) acc[j] = c1s[j];
    const uint32* rowb = a3b + (long)n * 32;
    for (int kk = 0; kk < 8; ++kk) {
      uint4 q = *(const uint4*)(rowb + kk * 4);
      float rv0 = b2f_lo(q.x), rv1 = b2f_hi(q.x);
      float rv2 = b2f_lo(q.y), rv3 = b2f_hi(q.y);
      float rv4 = b2f_lo(q.z), rv5 = b2f_hi(q.z);
      float rv6 = b2f_lo(q.w), rv7 = b2f_hi(q.w);
      const float* r0 = &C1s[(8 * kk + 0) * 32];
      const float* r1 = &C1s[(8 * kk + 1) * 32];
      const float* r2 = &C1s[(8 * kk + 2) * 32];
      const float* r3 = &C1s[(8 * kk + 3) * 32];
      const float* r4 = &C1s[(8 * kk + 4) * 32];
      const float* r5 = &C1s[(8 * kk + 5) * 32];
      const float* r6 = &C1s[(8 * kk + 6) * 32];
      const float* r7 = &C1s[(8 * kk + 7) * 32];
#pragma unroll
      for (int j = 0; j < 32; ++j)
        acc[j] += rv0 * r0[j] + rv1 * r1[j] + rv2 * r2[j] + rv3 * r3[j] +
                  rv4 * r4[j] + rv5 * r5[j] + rv6 * r6[j] + rv7 * r7[j];
    }
    float a2[8];
#pragma unroll
    for (int j = 0; j < 8; ++j) a2[j] = b2s[j];
#pragma unroll
    for (int k = 0; k < 32; ++k) {
      float v = acc[k];
      v = v >= 0.f ? v : 0.01f * v;
#pragma unroll
      for (int j = 0; j < 8; ++j) a2[j] += v * W2s[k * 8 + j];
    }
    float s = b3s;
#pragma unroll
    for (int k = 0; k < 8; ++k) {
      float v = a2[k];
      v = v >= 0.f ? v : 0.01f * v;
      s += v * W3s[k];
    }
    dval = s;
    out[n] = dval;        // z_orth (unscaled)
    out[NN + n] = dval;   // mu_orth (z == mu in eval mode)
  }
  __shared__ float red[256];
  red[threadIdx.x] = dval * dval;
  __syncthreads();
  for (int off = 128; off > 0; off >>= 1) {
    if (threadIdx.x < off) red[threadIdx.x] += red[threadIdx.x + off];
    __syncthreads();
  }
  if (threadIdx.x == 0) atomicAdd(norm_acc, red[0]);
}

__global__ __launch_bounds__(256) void k_scale(float* __restrict__ out,
                                               const float* __restrict__ norm_acc) {
  int i = blockIdx.x * 256 + threadIdx.x;
  if (i < 2 * NN) {
    float nrm = sqrtf(*norm_acc);
    float sc = 1.0f / fmaxf(nrm, 1e-8f);
    out[i] *= sc;
  }
}

extern "C" void kernel_launch(void* const* d_in, const int* in_sizes, int n_in,
                              void* d_out, int out_size, void* d_ws, size_t ws_size,
                              hipStream_t stream) {
  const float* x   = (const float*)d_in[0];
  const int*   hei = (const int*)d_in[1];  // [2, NP]
  const int* nidx = hei;
  const int* eidx = hei + NP;
  const float* W1  = (const float*)d_in[2];
  const float* b1  = (const float*)d_in[3];
  const float* g1  = (const float*)d_in[4];
  const float* be1 = (const float*)d_in[5];
  const float* W2  = (const float*)d_in[6];
  const float* b2  = (const float*)d_in[7];
  const float* Wmu = (const float*)d_in[8];
  const float* bmu = (const float*)d_in[9];
  const float* Wlv = (const float*)d_in[10];
  const float* blv = (const float*)d_in[11];
  const float* dW1 = (const float*)d_in[12];
  const float* db1 = (const float*)d_in[13];
  const float* dW2 = (const float*)d_in[14];
  const float* db2 = (const float*)d_in[15];
  const float* dW3 = (const float*)d_in[16];
  const float* db3 = (const float*)d_in[17];
  float* out = (float*)d_out;

  int*    wi = (int*)d_ws;
  float*  wf = (float*)d_ws;
  uint32* wu = (uint32*)d_ws;

  // zero gcurE/gcurN/norm (words 0 .. 1087)
  hipMemsetAsync(d_ws, 0, (size_t)1088 * 4, stream);

  // front: bucketize + compose + cast in one launch
  k_front<<<NBK + 1 + CASTB, 256, 0, stream>>>(nidx, eidx,
                                               wi + O_GCURE, wi + O_GCURN,
                                               wi + O_BKTE, wi + O_BKTN,
                                               Wmu, bmu, dW1, db1,
                                               wf + O_C1, wf + O_C1B,
                                               x, wu + O_XB);
  k_csr2<<<2 * NBK, 256, 0, stream>>>(wi + O_GCURE, wi + O_GCURN,
                                      wi + O_BKTE, wi + O_BKTN,
                                      wi + O_CSRE, wi + O_CSRN,
                                      wi + O_DEGE, wi + O_DEGN,
                                      wf + O_BINV, wf + O_DINV);

  const int G32 = (NE * 2 + 255) / 256;   // edge agg 32-wide (2 lanes/seg)
  const int G64 = (NE * 4 + 255) / 256;   // edge agg 64-wide (4 lanes/seg)

  // layer 1
  k_seg_agg<32><<<G32, 256, 0, stream>>>(wu + O_XB, wi + O_CSRE,
                                         wi + O_DEGE, wf + O_BINV, wu + O_HE);
  k_agg_ln<<<(NN + 127) / 128, 256, 0, stream>>>(wu + O_HE, wi + O_CSRN,
                                                 wi + O_DEGN, wf + O_DINV,
                                                 W1, b1, g1, be1, wu + O_T);
  // layer 2
  k_seg_agg<64><<<G64, 256, 0, stream>>>(wu + O_T, wi + O_CSRE,
                                         wi + O_DEGE, wf + O_BINV, wu + O_HE);
  k_agg_lk<<<(NN + 63) / 64, 256, 0, stream>>>(wu + O_HE, wi + O_CSRN,
                                               wi + O_DEGN, wf + O_DINV,
                                               W2, b2, wu + O_T);
  // heads: fused node-agg + lv GEMM (+ bf16 a3 side-write), then decode
  k_seg_agg<64><<<G64, 256, 0, stream>>>(wu + O_T, wi + O_CSRE,
                                         wi + O_DEGE, wf + O_BINV, wu + O_HE);
  k_agg_lv<<<(NN + 63) / 64, 256, 0, stream>>>(wu + O_HE, wi + O_CSRN,
                                               wi + O_DEGN, wf + O_DINV,
                                               Wlv, blv, wu + O_A, out + 2 * NN);
  k_decode<<<(NN + 255) / 256, 256, 0, stream>>>(wu + O_A, wf + O_C1, wf + O_C1B,
                                                 dW2, db2, dW3, db3,
                                                 out, wf + O_NORM);
  k_scale<<<(2 * NN + 255) / 256, 256, 0, stream>>>(out, wf + O_NORM);
}

// Round 6
// 359.387 us; speedup vs baseline: 1.0898x; 1.0898x over previous
//
#include <hip/hip_runtime.h>

// HypergraphModel on MI355X.
// R18: R14 structure (best verified: 366.8us) + COMPACT CSR.
//      R15-R17 refuted scheduling/MLP levers; counters point at the L2
//      miss/fill path (~2.7 TB/s) as the limiter -> cut bytes.
//      Padded CSR (192B stride/seg) touched ~20MB of index lines per gather
//      launch; compact 16B-aligned-per-segment CSR touches ~7MB. Built in
//      k_csr2 via LDS prefix-scan of per-segment sizes (rounded to 4 ints)
//      + one global atomicAdd per bucket; off[] per side. Per-segment
//      summation order unchanged -> same numerics as R14.

#define NN 100000
#define NE 100000
#define NP 1600000
#define NBK  391   // buckets per side (256 ids each); NBK*256 = 100,096
#define BCAP 4608  // bucket cap (mean 4096, +8 sigma)

// ws offsets in 4-byte words (sizes in words) — non-overlapping:
#define O_GCURE 0              // 512  (zeroed)
#define O_GCURN 512            // 512  (zeroed)
#define O_NORM  1024           // 1    (zeroed)
#define O_GBASE 1025           // 2    (zeroed) compact-CSR base counters E/N
#define O_DEGE  1088           // 100,000
#define O_DEGN  101088         // 100,000
#define O_BINV  201088         // 100,000
#define O_DINV  301088         // 100,000
#define O_BKTE  401088         // NBK*BCAP = 1,801,728
#define O_BKTN  2202816        // 1,801,728
#define O_CSRE  4004544        // compact data (<2M used of 4.6M)
#define O_OFFE  8604544        // 100,000 (ends 8,704,544 < O_CSRN)
#define O_CSRN  8804544        // compact data (<2M used of 4.6M)
#define O_OFFN  13404544       // 100,000 (ends 13,504,544 < O_XB)
#define O_XB    13604544       // bf16 100000x32 = 1,600,000 words
#define O_T     15204544       // bf16 100000x64 = 3,200,000 words
#define O_HE    18404544       // bf16 100000x64 = 3,200,000 words
#define O_C1    21604544       // fp32 64x32 = 2,048
#define O_C1B   21606592       // fp32 32
#define O_A     21606624       // bf16 100000x64 = 1,600,000 words
// end 23,206,624 words = 92.8 MB (proven envelope)

typedef unsigned int uint32;

__device__ __forceinline__ float b2f_lo(uint32 u) { return __uint_as_float(u << 16); }
__device__ __forceinline__ float b2f_hi(uint32 u) { return __uint_as_float(u & 0xFFFF0000u); }
__device__ __forceinline__ uint32 f2b(float f) {  // RNE fp32 -> bf16
  uint32 b = __float_as_uint(f);
  return (b + 0x7FFFu + ((b >> 16) & 1u)) >> 16;
}
__device__ __forceinline__ uint32 pack2(float lo, float hi) {
  return f2b(lo) | (f2b(hi) << 16);
}

// 8-elem gather-accumulate over a compact-CSR segment (bf16 rows, ROWU uints
// per row, 16B per lane). a[0..7] must be zeroed by caller.
// R14 pipeline: index prefetch + single predicated remainder window.
// beg is 16B-aligned; reads may touch up to csr[end+7] (next segment's valid
// memory / slack) but those values are never used as addresses.
template <int ROWU>
__device__ __forceinline__ void gather8(const uint32* __restrict__ base,
                                        const int* __restrict__ csr,
                                        int beg, int end, float* a) {
#define ACC(q)                                        \
  a[0] += b2f_lo(q.x); a[1] += b2f_hi(q.x);           \
  a[2] += b2f_lo(q.y); a[3] += b2f_hi(q.y);           \
  a[4] += b2f_lo(q.z); a[5] += b2f_hi(q.z);           \
  a[6] += b2f_lo(q.w); a[7] += b2f_hi(q.w);
  int p = beg;
  int nfull = (end - beg) >> 3;
  int4 ia, ib;
  bool have = false;
  if (nfull > 0) {
    ia = *(const int4*)(csr + p);
    ib = *(const int4*)(csr + p + 4);
    for (int k = 0; k < nfull; ++k) {
      uint4 q0 = *(const uint4*)(base + (long)ia.x * ROWU);
      uint4 q1 = *(const uint4*)(base + (long)ia.y * ROWU);
      uint4 q2 = *(const uint4*)(base + (long)ia.z * ROWU);
      uint4 q3 = *(const uint4*)(base + (long)ia.w * ROWU);
      uint4 q4 = *(const uint4*)(base + (long)ib.x * ROWU);
      uint4 q5 = *(const uint4*)(base + (long)ib.y * ROWU);
      uint4 q6 = *(const uint4*)(base + (long)ib.z * ROWU);
      uint4 q7 = *(const uint4*)(base + (long)ib.w * ROWU);
      // prefetch next batch's indices while rows are in flight.
      ia = *(const int4*)(csr + p + 8);
      ib = *(const int4*)(csr + p + 12);
      ACC(q0) ACC(q1) ACC(q2) ACC(q3) ACC(q4) ACC(q5) ACC(q6) ACC(q7)
      p += 8;
    }
    have = true;
  }
  int rem = end - p;  // 0..7
  if (rem > 0) {
    if (!have) {
      ia = *(const int4*)(csr + p);
      ib = *(const int4*)(csr + p + 4);
    }
    // ia/ib hold csr[p..p+7]; issue all valid row loads before any ACC.
    uint4 z = {0u, 0u, 0u, 0u};
    uint4 q0 = z, q1 = z, q2 = z, q3 = z, q4 = z, q5 = z, q6 = z;
    q0 = *(const uint4*)(base + (long)ia.x * ROWU);
    if (rem > 1) q1 = *(const uint4*)(base + (long)ia.y * ROWU);
    if (rem > 2) q2 = *(const uint4*)(base + (long)ia.z * ROWU);
    if (rem > 3) q3 = *(const uint4*)(base + (long)ia.w * ROWU);
    if (rem > 4) q4 = *(const uint4*)(base + (long)ib.x * ROWU);
    if (rem > 5) q5 = *(const uint4*)(base + (long)ib.y * ROWU);
    if (rem > 6) q6 = *(const uint4*)(base + (long)ib.z * ROWU);
    ACC(q0) ACC(q1) ACC(q2) ACC(q3) ACC(q4) ACC(q5) ACC(q6)
  }
#undef ACC
}

// ---- k_front: bucketize (blocks 0..NBK-1) + compose (block NBK) +
//      cast x->bf16 (blocks NBK+1 ..). All independent.
#define CASTB ((NN * 32 / 8 + 255) / 256)  // 1563
__global__ __launch_bounds__(256) void k_front(const int* __restrict__ nidx,
                                               const int* __restrict__ eidx,
                                               int* __restrict__ gcurE,
                                               int* __restrict__ gcurN,
                                               int* __restrict__ bktE,
                                               int* __restrict__ bktN,
                                               const float* __restrict__ Wmu,
                                               const float* __restrict__ bmu,
                                               const float* __restrict__ dW1,
                                               const float* __restrict__ db1,
                                               float* __restrict__ C1,
                                               float* __restrict__ c1,
                                               const float* __restrict__ x,
                                               uint32* __restrict__ xb) {
  __shared__ int cntE[NBK], cntN[NBK], curE[NBK], curN[NBK];
  if (blockIdx.x < NBK) {
    for (int i = threadIdx.x; i < NBK; i += 256) { cntE[i] = 0; cntN[i] = 0; }
    __syncthreads();
    int base = blockIdx.x * 4096 + threadIdx.x * 16;
    int n[16], e[16];
    int cnt = 0;
    if (base + 16 <= NP) {
#pragma unroll
      for (int q = 0; q < 4; ++q) {
        int4 a = *(const int4*)(nidx + base + 4 * q);
        int4 b = *(const int4*)(eidx + base + 4 * q);
        n[4 * q + 0] = a.x; n[4 * q + 1] = a.y; n[4 * q + 2] = a.z; n[4 * q + 3] = a.w;
        e[4 * q + 0] = b.x; e[4 * q + 1] = b.y; e[4 * q + 2] = b.z; e[4 * q + 3] = b.w;
      }
      cnt = 16;
    } else {
      for (int i = 0; i < 16 && base + i < NP; ++i) {
        n[i] = nidx[base + i];
        e[i] = eidx[base + i];
        ++cnt;
      }
    }
    for (int i = 0; i < cnt; ++i) {
      atomicAdd(&cntE[e[i] >> 8], 1);
      atomicAdd(&cntN[n[i] >> 8], 1);
    }
    __syncthreads();
    for (int i = threadIdx.x; i < NBK; i += 256) {
      curE[i] = atomicAdd(&gcurE[i], cntE[i]);
      curN[i] = atomicAdd(&gcurN[i], cntN[i]);
    }
    __syncthreads();
    for (int i = 0; i < cnt; ++i) {
      int be = e[i] >> 8, bn = n[i] >> 8;
      int se = atomicAdd(&curE[be], 1);
      if (se < BCAP) bktE[be * BCAP + se] = ((e[i] & 255) << 24) | n[i];
      int sn = atomicAdd(&curN[bn], 1);
      if (sn < BCAP) bktN[bn * BCAP + sn] = ((n[i] & 255) << 24) | e[i];
    }
  } else if (blockIdx.x == NBK) {
    int t = threadIdx.x;
    for (int idx = t; idx < 64 * 32; idx += 256) {
      int i = idx >> 5, j = idx & 31;
      float s = 0.f;
      for (int k = 0; k < 64; ++k) s += Wmu[i * 64 + k] * dW1[k * 32 + j];
      C1[idx] = s;
    }
    if (t < 32) {
      float s = db1[t];
      for (int k = 0; k < 64; ++k) s += bmu[k] * dW1[k * 32 + t];
      c1[t] = s;
    }
  } else {
    int t = (blockIdx.x - NBK - 1) * 256 + threadIdx.x;
    if (t < NN * 32 / 8) {
      const float4 f0 = *(const float4*)(x + (long)t * 8);
      const float4 f1 = *(const float4*)(x + (long)t * 8 + 4);
      uint4 o;
      o.x = pack2(f0.x, f0.y);
      o.y = pack2(f0.z, f0.w);
      o.z = pack2(f1.x, f1.y);
      o.w = pack2(f1.z, f1.w);
      *(uint4*)(xb + (long)t * 4) = o;
    }
  }
}

// ---- Pass B: per-bucket COMPACT CSR build + deg + 1/deg + off.
// Per-segment size rounded to 4 ints (16B-aligned int4 index loads);
// bucket base via one global atomicAdd; per-segment offsets via LDS scan.
__global__ __launch_bounds__(256) void k_csr2(const int* __restrict__ gcurE,
                                              const int* __restrict__ gcurN,
                                              const int* __restrict__ bktE,
                                              const int* __restrict__ bktN,
                                              int* __restrict__ csrE,
                                              int* __restrict__ csrN,
                                              int* __restrict__ offE,
                                              int* __restrict__ offN,
                                              int* __restrict__ degE,
                                              int* __restrict__ degN,
                                              float* __restrict__ invE,
                                              float* __restrict__ invN,
                                              int* __restrict__ gbase) {
  int bb = blockIdx.x;
  bool es = bb < NBK;
  int b = es ? bb : bb - NBK;
  const int* gcur = es ? gcurE : gcurN;
  const int* bkt  = es ? bktE : bktN;
  int*   csr = es ? csrE : csrN;
  int*   off = es ? offE : offN;
  int*   deg = es ? degE : degN;
  float* inv = es ? invE : invN;
  int*   gb  = gbase + (es ? 0 : 1);

  __shared__ int ent[BCAP];
  __shared__ int cnt[256], cur[256], sc[256];
  __shared__ int base_s;
  int t = threadIdx.x;
  int m = gcur[b];
  if (m > BCAP) m = BCAP;
  for (int i = t; i < m; i += 256) ent[i] = bkt[b * BCAP + i];
  cnt[t] = 0;
  __syncthreads();
  for (int i = t; i < m; i += 256)
    atomicAdd(&cnt[((unsigned)ent[i]) >> 24], 1);
  __syncthreads();
  int d = cnt[t];
  int rsize = (d + 3) & ~3;  // 16B-aligned segment slot
  sc[t] = rsize;
  __syncthreads();
  // inclusive scan over 256 entries (Hillis-Steele)
  for (int o = 1; o < 256; o <<= 1) {
    int v = (t >= o) ? sc[t - o] : 0;
    __syncthreads();
    sc[t] += v;
    __syncthreads();
  }
  if (t == 255) base_s = atomicAdd(gb, sc[255]);
  __syncthreads();
  int myoff = base_s + sc[t] - rsize;
  int id = (b << 8) + t;
  if (id < NN) {  // NN == NE
    deg[id] = d;
    inv[id] = d > 0 ? 1.0f / (float)d : 0.0f;
    off[id] = myoff;
  }
  cur[t] = 0;
  __syncthreads();
  for (int i = t; i < m; i += 256) {
    unsigned v = (unsigned)ent[i];
    int loc = v >> 24;
    int payload = v & 0xFFFFFF;
    int slot = atomicAdd(&cur[loc], 1);
    int lbeg = base_s + sc[loc] - ((cnt[loc] + 3) & ~3);
    csr[lbeg + slot] = payload;
  }
}

// Edge-side gather-reduce, bf16 in / bf16 out (compact CSR).
template <int W>
__global__ __launch_bounds__(256) void k_seg_agg(const uint32* __restrict__ tb,
                                                 const int* __restrict__ csr,
                                                 const int* __restrict__ off,
                                                 const int* __restrict__ deg,
                                                 const float* __restrict__ inv,
                                                 uint32* __restrict__ dstb) {
  constexpr int LANES = W / 8;
  constexpr int ROWU = W / 2;
  int g = blockIdx.x * 256 + threadIdx.x;
  int s = g / LANES;
  int lane = g % LANES;
  if (s >= NE) return;
  int d = deg[s];
  int beg = off[s];
  float a[8] = {0.f, 0.f, 0.f, 0.f, 0.f, 0.f, 0.f, 0.f};
  gather8<ROWU>(tb + (long)lane * 4, csr, beg, beg + d, a);
  float sc = inv[s];
  uint4 o;
  o.x = pack2(a[0] * sc, a[1] * sc);
  o.y = pack2(a[2] * sc, a[3] * sc);
  o.z = pack2(a[4] * sc, a[5] * sc);
  o.w = pack2(a[6] * sc, a[7] * sc);
  *(uint4*)(dstb + (long)s * ROWU + lane * 4) = o;
}

// ---- Fused node-agg (32-wide) + GEMM(32->64) + LN + leaky -> bf16 t.
#define R32 40
__global__ __launch_bounds__(256) void k_agg_ln(
    const uint32* __restrict__ he, const int* __restrict__ csr,
    const int* __restrict__ off,
    const int* __restrict__ deg, const float* __restrict__ inv,
    const float* __restrict__ W1, const float* __restrict__ b1,
    const float* __restrict__ g1, const float* __restrict__ be1,
    uint32* __restrict__ h) {
  __shared__ float Ws[32 * 64];
  __shared__ __align__(16) float rows[64 * R32];
  for (int i = threadIdx.x; i < 32 * 64; i += 256) Ws[i] = W1[i];
  int sl = threadIdx.x >> 2;
  int lane = threadIdx.x & 3;
  int s = blockIdx.x * 64 + sl;
  if (s < NN) {
    int d = deg[s];
    int beg = off[s];
    float a[8] = {0.f, 0.f, 0.f, 0.f, 0.f, 0.f, 0.f, 0.f};
    gather8<16>(he + (long)lane * 4, csr, beg, beg + d, a);
    float sc = inv[s];
    float4 o0 = {a[0] * sc, a[1] * sc, a[2] * sc, a[3] * sc};
    float4 o1 = {a[4] * sc, a[5] * sc, a[6] * sc, a[7] * sc};
    *(float4*)(&rows[sl * R32 + lane * 8]) = o0;
    *(float4*)(&rows[sl * R32 + lane * 8 + 4]) = o1;
  }
  __syncthreads();
#pragma unroll
  for (int pass = 0; pass < 4; ++pass) {
    int rl = pass * 16 + (threadIdx.x >> 4);
    int r = blockIdx.x * 64 + rl;
    int l = (threadIdx.x & 15) * 4;
    float vx = b1[l + 0], vy = b1[l + 1], vz = b1[l + 2], vw = b1[l + 3];
    const float* row = &rows[rl * R32];
#pragma unroll
    for (int kk = 0; kk < 8; ++kk) {
      float4 rv = *(const float4*)(row + 4 * kk);
      const float* w0 = &Ws[(4 * kk + 0) * 64 + l];
      const float* w1 = &Ws[(4 * kk + 1) * 64 + l];
      const float* w2 = &Ws[(4 * kk + 2) * 64 + l];
      const float* w3 = &Ws[(4 * kk + 3) * 64 + l];
      vx += rv.x * w0[0] + rv.y * w1[0] + rv.z * w2[0] + rv.w * w3[0];
      vy += rv.x * w0[1] + rv.y * w1[1] + rv.z * w2[1] + rv.w * w3[1];
      vz += rv.x * w0[2] + rv.y * w1[2] + rv.z * w2[2] + rv.w * w3[2];
      vw += rv.x * w0[3] + rv.y * w1[3] + rv.z * w2[3] + rv.w * w3[3];
    }
    float sm = vx + vy + vz + vw;
    float s2 = vx * vx + vy * vy + vz * vz + vw * vw;
    for (int m = 1; m <= 8; m <<= 1) {
      sm += __shfl_xor(sm, m, 64);
      s2 += __shfl_xor(s2, m, 64);
    }
    float mean = sm * (1.0f / 64.0f);
    float var = s2 * (1.0f / 64.0f) - mean * mean;
    float rstd = rsqrtf(var + 1e-5f);
    if (r < NN) {
      float ox = (vx - mean) * rstd * g1[l + 0] + be1[l + 0];
      float oy = (vy - mean) * rstd * g1[l + 1] + be1[l + 1];
      float oz = (vz - mean) * rstd * g1[l + 2] + be1[l + 2];
      float ow = (vw - mean) * rstd * g1[l + 3] + be1[l + 3];
      ox = ox >= 0.f ? ox : 0.01f * ox;
      oy = oy >= 0.f ? oy : 0.01f * oy;
      oz = oz >= 0.f ? oz : 0.01f * oz;
      ow = ow >= 0.f ? ow : 0.01f * ow;
      uint2 o = {pack2(ox, oy), pack2(oz, ow)};
      *(uint2*)(h + (long)r * 32 + (l >> 1)) = o;
    }
  }
}

// ---- Fused node-agg (64-wide) + GEMM(64->64) + leaky -> bf16 t.
#define R64 72
__global__ __launch_bounds__(256) void k_agg_lk(
    const uint32* __restrict__ he, const int* __restrict__ csr,
    const int* __restrict__ off,
    const int* __restrict__ deg, const float* __restrict__ inv,
    const float* __restrict__ W2, const float* __restrict__ b2,
    uint32* __restrict__ h2) {
  __shared__ float Ws[64 * 64];
  __shared__ __align__(16) float rows[32 * R64];
  for (int i = threadIdx.x; i < 64 * 64; i += 256) Ws[i] = W2[i];
  int sl = threadIdx.x >> 3;
  int lane = threadIdx.x & 7;
  int s = blockIdx.x * 32 + sl;
  if (s < NN) {
    int d = deg[s];
    int beg = off[s];
    float a[8] = {0.f, 0.f, 0.f, 0.f, 0.f, 0.f, 0.f, 0.f};
    gather8<32>(he + (long)lane * 4, csr, beg, beg + d, a);
    float sc = inv[s];
    float4 o0 = {a[0] * sc, a[1] * sc, a[2] * sc, a[3] * sc};
    float4 o1 = {a[4] * sc, a[5] * sc, a[6] * sc, a[7] * sc};
    *(float4*)(&rows[sl * R64 + lane * 8]) = o0;
    *(float4*)(&rows[sl * R64 + lane * 8 + 4]) = o1;
  }
  __syncthreads();
#pragma unroll
  for (int pass = 0; pass < 2; ++pass) {
    int rl = pass * 16 + (threadIdx.x >> 4);
    int r = blockIdx.x * 32 + rl;
    int l = (threadIdx.x & 15) * 4;
    float vx = b2[l + 0], vy = b2[l + 1], vz = b2[l + 2], vw = b2[l + 3];
    const float* row = &rows[rl * R64];
#pragma unroll
    for (int kk = 0; kk < 16; ++kk) {
      float4 rv = *(const float4*)(row + 4 * kk);
      const float* w0 = &Ws[(4 * kk + 0) * 64 + l];
      const float* w1 = &Ws[(4 * kk + 1) * 64 + l];
      const float* w2 = &Ws[(4 * kk + 2) * 64 + l];
      const float* w3 = &Ws[(4 * kk + 3) * 64 + l];
      vx += rv.x * w0[0] + rv.y * w1[0] + rv.z * w2[0] + rv.w * w3[0];
      vy += rv.x * w0[1] + rv.y * w1[1] + rv.z * w2[1] + rv.w * w3[1];
      vz += rv.x * w0[2] + rv.y * w1[2] + rv.z * w2[2] + rv.w * w3[2];
      vw += rv.x * w0[3] + rv.y * w1[3] + rv.z * w2[3] + rv.w * w3[3];
    }
    if (r < NN) {
      vx = vx >= 0.f ? vx : 0.01f * vx;
      vy = vy >= 0.f ? vy : 0.01f * vy;
      vz = vz >= 0.f ? vz : 0.01f * vz;
      vw = vw >= 0.f ? vw : 0.01f * vw;
      uint2 o = {pack2(vx, vy), pack2(vz, vw)};
      *(uint2*)(h2 + (long)r * 32 + (l >> 1)) = o;
    }
  }
}

// ---- Fused node-agg (64-wide) + logvar GEMM; emits bf16 a3 for decode.
__global__ __launch_bounds__(256) void k_agg_lv(
    const uint32* __restrict__ he, const int* __restrict__ csr,
    const int* __restrict__ off,
    const int* __restrict__ deg, const float* __restrict__ inv,
    const float* __restrict__ Wlv, const float* __restrict__ blv,
    uint32* __restrict__ a3b, float* __restrict__ lv) {
  __shared__ float Ws[64 * 64];
  __shared__ __align__(16) float rows[32 * R64];
  for (int i = threadIdx.x; i < 64 * 64; i += 256) Ws[i] = Wlv[i];
  int sl = threadIdx.x >> 3;
  int lane = threadIdx.x & 7;
  int s = blockIdx.x * 32 + sl;
  if (s < NN) {
    int d = deg[s];
    int beg = off[s];
    float a[8] = {0.f, 0.f, 0.f, 0.f, 0.f, 0.f, 0.f, 0.f};
    gather8<32>(he + (long)lane * 4, csr, beg, beg + d, a);
    float sc = inv[s];
    float4 o0 = {a[0] * sc, a[1] * sc, a[2] * sc, a[3] * sc};
    float4 o1 = {a[4] * sc, a[5] * sc, a[6] * sc, a[7] * sc};
    *(float4*)(&rows[sl * R64 + lane * 8]) = o0;
    *(float4*)(&rows[sl * R64 + lane * 8 + 4]) = o1;
    // bf16 a3 side-write for k_decode (uint4 = 8 bf16 per lane)
    uint4 ob;
    ob.x = pack2(o0.x, o0.y);
    ob.y = pack2(o0.z, o0.w);
    ob.z = pack2(o1.x, o1.y);
    ob.w = pack2(o1.z, o1.w);
    *(uint4*)(a3b + (long)s * 32 + lane * 4) = ob;
  }
  __syncthreads();
#pragma unroll
  for (int pass = 0; pass < 2; ++pass) {
    int rl = pass * 16 + (threadIdx.x >> 4);
    int r = blockIdx.x * 32 + rl;
    int l = (threadIdx.x & 15) * 4;
    float vx = blv[l + 0], vy = blv[l + 1], vz = blv[l + 2], vw = blv[l + 3];
    const float* row = &rows[rl * R64];
#pragma unroll
    for (int kk = 0; kk < 16; ++kk) {
      float4 rv = *(const float4*)(row + 4 * kk);
      const float* w0 = &Ws[(4 * kk + 0) * 64 + l];
      const float* w1 = &Ws[(4 * kk + 1) * 64 + l];
      const float* w2 = &Ws[(4 * kk + 2) * 64 + l];
      const float* w3 = &Ws[(4 * kk + 3) * 64 + l];
      vx += rv.x * w0[0] + rv.y * w1[0] + rv.z * w2[0] + rv.w * w3[0];
      vy += rv.x * w0[1] + rv.y * w1[1] + rv.z * w2[1] + rv.w * w3[1];
      vz += rv.x * w0[2] + rv.y * w1[2] + rv.z * w2[2] + rv.w * w3[2];
      vw += rv.x * w0[3] + rv.y * w1[3] + rv.z * w2[3] + rv.w * w3[3];
    }
    if (r < NN) {
      float4 o = {vx, vy, vz, vw};
      *(float4*)(&lv[(long)r * 64 + l]) = o;
    }
  }
}

// decode from bf16 a3 via composed C1/c1; one thread per row; norm accumulate.
__global__ __launch_bounds__(256) void k_decode(
    const uint32* __restrict__ a3b, const float* __restrict__ C1,
    const float* __restrict__ c1, const float* __restrict__ dW2,
    const float* __restrict__ db2, const float* __restrict__ dW3,
    const float* __restrict__ db3, float* __restrict__ out,
    float* __restrict__ norm_acc) {
  __shared__ float C1s[64 * 32];
  __shared__ float W2s[32 * 8];
  __shared__ float W3s[8];
  __shared__ float c1s[32];
  __shared__ float b2s[8];
  __shared__ float b3s;
  for (int i = threadIdx.x; i < 2048; i += 256) C1s[i] = C1[i];
  if (threadIdx.x < 256) W2s[threadIdx.x] = dW2[threadIdx.x];
  if (threadIdx.x < 32) c1s[threadIdx.x] = c1[threadIdx.x];
  if (threadIdx.x < 8) {
    W3s[threadIdx.x] = dW3[threadIdx.x];
    b2s[threadIdx.x] = db2[threadIdx.x];
  }
  if (threadIdx.x == 0) b3s = db3[0];
  __syncthreads();
  int n = blockIdx.x * 256 + threadIdx.x;
  float dval = 0.0f;
  if (n < NN) {
    float acc[32];
#pragma unroll
    for (int j = 0; j < 32; ++j) acc[j] = c1s[j];
    const uint32* rowb = a3b + (long)n * 32;
    for (int kk = 0; kk < 8; ++kk) {
      uint4 q = *(const uint4*)(rowb + kk * 4);
      float rv0 = b2f_lo(q.x), rv1 = b2f_hi(q.x);
      float rv2 = b2f_lo(q.y), rv3 = b2f_hi(q.y);
      float rv4 = b2f_lo(q.z), rv5 = b2f_hi(q.z);
      float rv6 = b2f_lo(q.w), rv7 = b2f_hi(q.w);
      const float* r0 = &C1s[(8 * kk + 0) * 32];
      const float* r1 = &C1s[(8 * kk + 1) * 32];
      const float* r2 = &C1s[(8 * kk + 2) * 32];
      const float* r3 = &C1s[(8 * kk + 3) * 32];
      const float* r4 = &C1s[(8 * kk + 4) * 32];
      const float* r5 = &C1s[(8 * kk + 5) * 32];
      const float* r6 = &C1s[(8 * kk + 6) * 32];
      const float* r7 = &C1s[(8 * kk + 7) * 32];
#pragma unroll
      for (int j = 0; j < 32; ++j)
        acc[j] += rv0 * r0[j] + rv1 * r1[j] + rv2 * r2[j] + rv3 * r3[j] +
                  rv4 * r4[j] + rv5 * r5[j] + rv6 * r6[j] + rv7 * r7[j];
    }
    float a2[8];
#pragma unroll
    for (int j = 0; j < 8; ++j) a2[j] = b2s[j];
#pragma unroll
    for (int k = 0; k < 32; ++k) {
      float v = acc[k];
      v = v >= 0.f ? v : 0.01f * v;
#pragma unroll
      for (int j = 0; j < 8; ++j) a2[j] += v * W2s[k * 8 + j];
    }
    float s = b3s;
#pragma unroll
    for (int k = 0; k < 8; ++k) {
      float v = a2[k];
      v = v >= 0.f ? v : 0.01f * v;
      s += v * W3s[k];
    }
    dval = s;
    out[n] = dval;        // z_orth (unscaled)
    out[NN + n] = dval;   // mu_orth (z == mu in eval mode)
  }
  __shared__ float red[256];
  red[threadIdx.x] = dval * dval;
  __syncthreads();
  for (int off = 128; off > 0; off >>= 1) {
    if (threadIdx.x < off) red[threadIdx.x] += red[threadIdx.x + off];
    __syncthreads();
  }
  if (threadIdx.x == 0) atomicAdd(norm_acc, red[0]);
}

__global__ __launch_bounds__(256) void k_scale(float* __restrict__ out,
                                               const float* __restrict__ norm_acc) {
  int i = blockIdx.x * 256 + threadIdx.x;
  if (i < 2 * NN) {
    float nrm = sqrtf(*norm_acc);
    float sc = 1.0f / fmaxf(nrm, 1e-8f);
    out[i] *= sc;
  }
}

extern "C" void kernel_launch(void* const* d_in, const int* in_sizes, int n_in,
                              void* d_out, int out_size, void* d_ws, size_t ws_size,
                              hipStream_t stream) {
  const float* x   = (const float*)d_in[0];
  const int*   hei = (const int*)d_in[1];  // [2, NP]
  const int* nidx = hei;
  const int* eidx = hei + NP;
  const float* W1  = (const float*)d_in[2];
  const float* b1  = (const float*)d_in[3];
  const float* g1  = (const float*)d_in[4];
  const float* be1 = (const float*)d_in[5];
  const float* W2  = (const float*)d_in[6];
  const float* b2  = (const float*)d_in[7];
  const float* Wmu = (const float*)d_in[8];
  const float* bmu = (const float*)d_in[9];
  const float* Wlv = (const float*)d_in[10];
  const float* blv = (const float*)d_in[11];
  const float* dW1 = (const float*)d_in[12];
  const float* db1 = (const float*)d_in[13];
  const float* dW2 = (const float*)d_in[14];
  const float* db2 = (const float*)d_in[15];
  const float* dW3 = (const float*)d_in[16];
  const float* db3 = (const float*)d_in[17];
  float* out = (float*)d_out;

  int*    wi = (int*)d_ws;
  float*  wf = (float*)d_ws;
  uint32* wu = (uint32*)d_ws;

  // zero gcurE/gcurN/norm/gbase (words 0 .. 1087)
  hipMemsetAsync(d_ws, 0, (size_t)1088 * 4, stream);

  // front: bucketize + compose + cast in one launch
  k_front<<<NBK + 1 + CASTB, 256, 0, stream>>>(nidx, eidx,
                                               wi + O_GCURE, wi + O_GCURN,
                                               wi + O_BKTE, wi + O_BKTN,
                                               Wmu, bmu, dW1, db1,
                                               wf + O_C1, wf + O_C1B,
                                               x, wu + O_XB);
  k_csr2<<<2 * NBK, 256, 0, stream>>>(wi + O_GCURE, wi + O_GCURN,
                                      wi + O_BKTE, wi + O_BKTN,
                                      wi + O_CSRE, wi + O_CSRN,
                                      wi + O_OFFE, wi + O_OFFN,
                                      wi + O_DEGE, wi + O_DEGN,
                                      wf + O_BINV, wf + O_DINV,
                                      wi + O_GBASE);

  const int G32 = (NE * 4 + 255) / 256;   // edge agg 32-wide
  const int G64 = (NE * 8 + 255) / 256;   // edge agg 64-wide

  // layer 1
  k_seg_agg<32><<<G32, 256, 0, stream>>>(wu + O_XB, wi + O_CSRE, wi + O_OFFE,
                                         wi + O_DEGE, wf + O_BINV, wu + O_HE);
  k_agg_ln<<<(NN + 63) / 64, 256, 0, stream>>>(wu + O_HE, wi + O_CSRN,
                                               wi + O_OFFN,
                                               wi + O_DEGN, wf + O_DINV,
                                               W1, b1, g1, be1, wu + O_T);
  // layer 2
  k_seg_agg<64><<<G64, 256, 0, stream>>>(wu + O_T, wi + O_CSRE, wi + O_OFFE,
                                         wi + O_DEGE, wf + O_BINV, wu + O_HE);
  k_agg_lk<<<(NN + 31) / 32, 256, 0, stream>>>(wu + O_HE, wi + O_CSRN,
                                               wi + O_OFFN,
                                               wi + O_DEGN, wf + O_DINV,
                                               W2, b2, wu + O_T);
  // heads: fused node-agg + lv GEMM (+ bf16 a3 side-write), then decode
  k_seg_agg<64><<<G64, 256, 0, stream>>>(wu + O_T, wi + O_CSRE, wi + O_OFFE,
                                         wi + O_DEGE, wf + O_BINV, wu + O_HE);
  k_agg_lv<<<(NN + 31) / 32, 256, 0, stream>>>(wu + O_HE, wi + O_CSRN,
                                               wi + O_OFFN,
                                               wi + O_DEGN, wf + O_DINV,
                                               Wlv, blv, wu + O_A, out + 2 * NN);
  k_decode<<<(NN + 255) / 256, 256, 0, stream>>>(wu + O_A, wf + O_C1, wf + O_C1B,
                                                 dW2, db2, dW3, db3,
                                                 out, wf + O_NORM);
  k_scale<<<(2 * NN + 255) / 256, 256, 0, stream>>>(out, wf + O_NORM);
}